// Round 1
// baseline (752.540 us; speedup 1.0000x reference)
//
#include <hip/hip_runtime.h>

#define TGT 2048
#define SRC 2048
#define BH 16
#define HD 64
#define BT 16
#define SROW 2056  // shorts per LDS S row (2048 + 8 pad, keeps 16B alignment)

typedef __bf16 bf16x8 __attribute__((ext_vector_type(8)));
typedef unsigned short ushortx8 __attribute__((ext_vector_type(8)));
typedef float floatx4 __attribute__((ext_vector_type(4)));

__device__ int g_mask_is_u8;

__device__ __forceinline__ unsigned short f2bf(float f) {
  unsigned u = __builtin_bit_cast(unsigned, f);
  u += 0x7FFFu + ((u >> 16) & 1u);   // RNE
  return (unsigned short)(u >> 16);
}
__device__ __forceinline__ float bf2f(unsigned short s) {
  unsigned u = ((unsigned)s) << 16;
  return __builtin_bit_cast(float, u);
}

__device__ __forceinline__ bf16x8 pack_bf8(float4 x, float4 y, float scale) {
  union { unsigned short u[8]; bf16x8 v; } fr;
  fr.u[0] = f2bf(x.x * scale); fr.u[1] = f2bf(x.y * scale);
  fr.u[2] = f2bf(x.z * scale); fr.u[3] = f2bf(x.w * scale);
  fr.u[4] = f2bf(y.x * scale); fr.u[5] = f2bf(y.y * scale);
  fr.u[6] = f2bf(y.z * scale); fr.u[7] = f2bf(y.w * scale);
  return fr.v;
}

// Detect whether the bool mask is stored as 1 byte/elem (numpy bool) or
// int32/elem. If int32 with values 0/1, every byte at idx%4!=0 is zero.
// Reading the first 4096 bytes is safe under both interpretations.
__global__ void detect_mask_fmt(const unsigned char* __restrict__ m) {
  __shared__ int any;
  if (threadIdx.x == 0) any = 0;
  __syncthreads();
  int local = 0;
  int base = threadIdx.x * 16;
#pragma unroll
  for (int i = 0; i < 16; ++i) {
    int idx = base + i;
    if (idx & 3) local |= m[idx];
  }
  if (local) atomicOr(&any, 1);
  __syncthreads();
  if (threadIdx.x == 0) g_mask_is_u8 = (any != 0);
}

__launch_bounds__(256, 2)
__global__ void attn_kernel(const float* __restrict__ q,
                            const float* __restrict__ k,
                            const float* __restrict__ v,
                            const unsigned char* __restrict__ mask8,
                            const int* __restrict__ mask32,
                            float* __restrict__ out0,
                            float* __restrict__ wout) {
  extern __shared__ char smem[];
  unsigned short* smS = (unsigned short*)smem;             // [BT][SROW] bf16
  float* pmaxArr = (float*)(smem + BT * SROW * 2);         // [16][64], reused as psum[16][16]
  float* rowmaxArr = pmaxArr + BT * 64;                    // [16]
  float* invArr = rowmaxArr + BT;                          // [16]

  const int bid = blockIdx.x;
  const int h = bid >> 7;              // 16 heads
  const int t0 = (bid & 127) * BT;     // 128 row tiles
  const int tid = threadIdx.x;
  const int wv = tid >> 6;
  const int lane = tid & 63;
  const int quad = lane >> 4;
  const int l16 = lane & 15;
  const bool is_u8 = (g_mask_is_u8 != 0);

  // ---- Phase A: Q fragments (A operand, scaled by 1/sqrt(64)) ----
  // A[m=lane&15][k=quad*8+j], k covers d; two MFMA k-steps for d=0..63.
  bf16x8 aq[2];
  {
    const float* qrow = q + (size_t)(t0 + l16) * (BH * HD) + h * HD + quad * 8;
#pragma unroll
    for (int st = 0; st < 2; ++st) {
      float4 x = *(const float4*)(qrow + st * 32);
      float4 y = *(const float4*)(qrow + st * 32 + 4);
      aq[st] = pack_bf8(x, y, 0.125f);
    }
  }

  // ---- Phase B: S = QK^T (masked), bf16 into LDS, running row max ----
  float rmax[4] = {-3.4e38f, -3.4e38f, -3.4e38f, -3.4e38f};
  const float* krow = k + h * HD + quad * 8;
  for (int st = wv; st < SRC / 16; st += 4) {
    const int sbase = st * 16;
    const float* kp = krow + (size_t)(sbase + l16) * (BH * HD);
    float4 x0 = *(const float4*)(kp);
    float4 y0 = *(const float4*)(kp + 4);
    float4 x1 = *(const float4*)(kp + 32);
    float4 y1 = *(const float4*)(kp + 36);
    bf16x8 bk0 = pack_bf8(x0, y0, 1.0f);
    bf16x8 bk1 = pack_bf8(x1, y1, 1.0f);
    floatx4 c = {0.f, 0.f, 0.f, 0.f};
    c = __builtin_amdgcn_mfma_f32_16x16x32_bf16(aq[0], bk0, c, 0, 0, 0);
    c = __builtin_amdgcn_mfma_f32_16x16x32_bf16(aq[1], bk1, c, 0, 0, 0);
    const int scol = sbase + l16;
#pragma unroll
    for (int r = 0; r < 4; ++r) {
      const int tl = quad * 4 + r;                    // C row = quad*4+reg
      const int midx = (t0 + tl) * SRC + scol;        // mask[0][t][s], True -> -1e8
      const int mv = is_u8 ? (int)mask8[midx] : mask32[midx];
      const float val = mv ? -1e8f : c[r];
      rmax[r] = fmaxf(rmax[r], val);
      const float oth = __shfl_xor(val, 1);           // partner column s^1
      if (!(l16 & 1)) {
        unsigned pk2 = (unsigned)f2bf(val) | ((unsigned)f2bf(oth) << 16);
        *(unsigned*)&smS[tl * SROW + scol] = pk2;
      }
    }
  }
  // partial row maxes -> pmax[row][wv*16+l16]
#pragma unroll
  for (int r = 0; r < 4; ++r)
    pmaxArr[(quad * 4 + r) * 64 + wv * 16 + l16] = rmax[r];
  __syncthreads();
  if (tid < BT) {
    float m = -3.4e38f;
    for (int j = 0; j < 64; ++j) m = fmaxf(m, pmaxArr[tid * 64 + j]);
    rowmaxArr[tid] = m;
  }
  __syncthreads();

  // ---- Phase C: e = exp(S - rowmax) in place, row sums ----
  {
    const int row = tid >> 4;
    const int cc = tid & 15;
    const float rm = rowmaxArr[row];
    float psum = 0.f;
    unsigned short* srow = smS + row * SROW;
    for (int kk = 0; kk < 16; ++kk) {
      const int col = cc * 8 + kk * 128;
      ushortx8 u = *(const ushortx8*)&srow[col];
      ushortx8 o;
#pragma unroll
      for (int i = 0; i < 8; ++i) {
        float e = __expf(bf2f(u[i]) - rm);
        psum += e;
        o[i] = f2bf(e);
      }
      *(ushortx8*)&srow[col] = o;
    }
    pmaxArr[row * 16 + cc] = psum;  // reuse as psum[16][16]
  }
  __syncthreads();
  if (tid < BT) {
    float s = 0.f;
    for (int j = 0; j < 16; ++j) s += pmaxArr[tid * 16 + j];
    invArr[tid] = 1.0f / s;
  }
  __syncthreads();

  // ---- Phase E: stream w = e * inv to global (stores fly during Phase D) ----
  {
    const int row = tid >> 4;
    const int cc = tid & 15;
    const float invv = invArr[row];
    float* wrow = wout + ((size_t)h * TGT + (t0 + row)) * SRC;
    const unsigned short* srow = smS + row * SROW;
    for (int kk = 0; kk < 16; ++kk) {
      const int col = cc * 8 + kk * 128;
      ushortx8 u = *(const ushortx8*)&srow[col];
      float4 a, b;
      a.x = bf2f(u[0]) * invv; a.y = bf2f(u[1]) * invv;
      a.z = bf2f(u[2]) * invv; a.w = bf2f(u[3]) * invv;
      b.x = bf2f(u[4]) * invv; b.y = bf2f(u[5]) * invv;
      b.z = bf2f(u[6]) * invv; b.w = bf2f(u[7]) * invv;
      *(float4*)&wrow[col] = a;
      *(float4*)&wrow[col + 4] = b;
    }
  }

  // ---- Phase D: out = (e V) * inv via MFMA; wave wv owns d-tile wv*16 ----
  {
    const int dbase = wv * 16;
    const float* vcol = v + h * HD + dbase + l16;
    floatx4 acc = {0.f, 0.f, 0.f, 0.f};
    for (int s0 = 0; s0 < SRC; s0 += 32) {
      ushortx8 ua = *(const ushortx8*)&smS[l16 * SROW + s0 + quad * 8];
      bf16x8 af = __builtin_bit_cast(bf16x8, ua);
      union { unsigned short u[8]; bf16x8 v; } bf;
      const int sr = s0 + quad * 8;
#pragma unroll
      for (int j = 0; j < 8; ++j)
        bf.u[j] = f2bf(vcol[(sr + j) * (BH * HD)]);
      acc = __builtin_amdgcn_mfma_f32_16x16x32_bf16(af, bf.v, acc, 0, 0, 0);
    }
#pragma unroll
    for (int r = 0; r < 4; ++r) {
      const int tl = quad * 4 + r;
      out0[((size_t)(t0 + tl) * BH + h) * HD + dbase + l16] = acc[r] * invArr[tl];
    }
  }
}

extern "C" void kernel_launch(void* const* d_in, const int* in_sizes, int n_in,
                              void* d_out, int out_size, void* d_ws, size_t ws_size,
                              hipStream_t stream) {
  const float* q = (const float*)d_in[0];
  const float* k = (const float*)d_in[1];
  const float* v = (const float*)d_in[2];
  const unsigned char* m8 = (const unsigned char*)d_in[3];
  const int* m32 = (const int*)d_in[3];
  float* out0 = (float*)d_out;
  float* wout = out0 + (size_t)TGT * BH * HD;

  const size_t shbytes = (size_t)BT * SROW * 2 + BT * 64 * 4 + BT * 4 + BT * 4;
  // >64KB dynamic LDS needs the attribute; idempotent, not a stream op (graph-safe).
  hipFuncSetAttribute((const void*)attn_kernel,
                      hipFuncAttributeMaxDynamicSharedMemorySize, (int)shbytes);

  detect_mask_fmt<<<1, 256, 0, stream>>>(m8);
  attn_kernel<<<dim3(BH * (TGT / BT)), dim3(256), shbytes, stream>>>(
      q, k, v, m8, m32, out0, wout);
}

// Round 2
// 432.084 us; speedup vs baseline: 1.7417x; 1.7417x over previous
//
#include <hip/hip_runtime.h>

#define TGT 2048
#define SRC 2048
#define BH 16
#define HD 64
#define BT 16
#define SROW 2056  // shorts per LDS S row (2048 + 8 pad, 16B-aligned rows)

typedef __bf16 bf16x8 __attribute__((ext_vector_type(8)));
typedef unsigned short ushortx8 __attribute__((ext_vector_type(8)));
typedef float floatx4 __attribute__((ext_vector_type(4)));

__device__ int g_mask_is_u8;

__device__ __forceinline__ unsigned short f2bf(float f) {
  unsigned u = __builtin_bit_cast(unsigned, f);
  u += 0x7FFFu + ((u >> 16) & 1u);   // RNE
  return (unsigned short)(u >> 16);
}
__device__ __forceinline__ float bf2f(unsigned short s) {
  unsigned u = ((unsigned)s) << 16;
  return __builtin_bit_cast(float, u);
}

// ---- prologue 1: mask format detect (1-byte numpy bool vs int32) ----
__global__ void detect_mask_fmt(const unsigned char* __restrict__ m) {
  __shared__ int any;
  if (threadIdx.x == 0) any = 0;
  __syncthreads();
  int local = 0;
  int base = threadIdx.x * 16;
#pragma unroll
  for (int i = 0; i < 16; ++i) {
    int idx = base + i;
    if (idx & 3) local |= m[idx];
  }
  if (local) atomicOr(&any, 1);
  __syncthreads();
  if (threadIdx.x == 0) g_mask_is_u8 = (any != 0);
}

// ---- prologue 2: Q (scaled 1/8) and K -> bf16, same layout ----
__global__ void cvt_qk(const float* __restrict__ q, const float* __restrict__ k,
                       unsigned short* __restrict__ qb, unsigned short* __restrict__ kb) {
  const int gid = blockIdx.x * 256 + threadIdx.x;   // grid = 2048 blocks
  const int half = TGT * BH * HD / 8;               // 262144 threads per tensor
  const float* src; unsigned short* dst; float sc;
  int idx;
  if (gid < half) { src = q; dst = qb; sc = 0.125f; idx = gid; }
  else            { src = k; dst = kb; sc = 1.0f;  idx = gid - half; }
  const float* p = src + (size_t)idx * 8;
  float4 a = *(const float4*)p;
  float4 b = *(const float4*)(p + 4);
  union { unsigned short u[8]; ushortx8 v; } o;
  o.u[0] = f2bf(a.x * sc); o.u[1] = f2bf(a.y * sc);
  o.u[2] = f2bf(a.z * sc); o.u[3] = f2bf(a.w * sc);
  o.u[4] = f2bf(b.x * sc); o.u[5] = f2bf(b.y * sc);
  o.u[6] = f2bf(b.z * sc); o.u[7] = f2bf(b.w * sc);
  *(ushortx8*)(dst + (size_t)idx * 8) = o.v;
}

// ---- prologue 3: V [s][h][d] fp32 -> vT [h][d][s] bf16 (64x64 LDS tiles) ----
__global__ void v_tr(const float* __restrict__ v, unsigned short* __restrict__ vt) {
  __shared__ unsigned short tile[64 * 72];  // [d][s], pad 72 keeps 16B rows
  const int h = blockIdx.x >> 5;
  const int s0 = (blockIdx.x & 31) * 64;
  const int tid = threadIdx.x;
  const int sr = tid >> 4, c = tid & 15;
#pragma unroll
  for (int p = 0; p < 4; ++p) {
    const int s = sr + p * 16;
    float4 f = *(const float4*)(v + (size_t)(s0 + s) * (BH * HD) + h * HD + c * 4);
    tile[(c * 4 + 0) * 72 + s] = f2bf(f.x);
    tile[(c * 4 + 1) * 72 + s] = f2bf(f.y);
    tile[(c * 4 + 2) * 72 + s] = f2bf(f.z);
    tile[(c * 4 + 3) * 72 + s] = f2bf(f.w);
  }
  __syncthreads();
  const int d = tid >> 2, q4 = tid & 3;
  ushortx8 o0 = *(const ushortx8*)&tile[d * 72 + q4 * 16];
  ushortx8 o1 = *(const ushortx8*)&tile[d * 72 + q4 * 16 + 8];
  unsigned short* dst = vt + (size_t)h * HD * SRC + (size_t)d * SRC + s0 + q4 * 16;
  *(ushortx8*)dst = o0;
  *(ushortx8*)(dst + 8) = o1;
}

// ---- main attention kernel: 512 threads, 8 waves ----
__launch_bounds__(512, 2)
__global__ void attn_kernel(const unsigned short* __restrict__ qb,
                            const unsigned short* __restrict__ kb,
                            const unsigned short* __restrict__ vtb,
                            const unsigned char* __restrict__ mask8,
                            const int* __restrict__ mask32,
                            float* __restrict__ out0,
                            float* __restrict__ wout) {
  extern __shared__ char smem[];
  unsigned short* smS = (unsigned short*)smem;           // [BT][SROW] bf16
  float* redArr = (float*)(smem + BT * SROW * 2);        // 1024 floats (reduce + partials)
  float* rowmaxArr = redArr + 1024;                      // [16]
  float* invArr = rowmaxArr + BT;                        // [16]

  const int bid = blockIdx.x;
  const int h = bid >> 7;
  const int t0 = (bid & 127) * BT;
  const int tid = threadIdx.x;
  const int wv = tid >> 6;
  const int lane = tid & 63;
  const int quad = lane >> 4;
  const int l16 = lane & 15;
  const bool is_u8 = (g_mask_is_u8 != 0);

  // ---- Phase A: Q fragments (bf16, pre-scaled) ----
  bf16x8 aq[2];
  {
    const unsigned short* qp = qb + (size_t)(t0 + l16) * (BH * HD) + h * HD + quad * 8;
    aq[0] = __builtin_bit_cast(bf16x8, *(const ushortx8*)qp);
    aq[1] = __builtin_bit_cast(bf16x8, *(const ushortx8*)(qp + 32));
  }

  // ---- Phase B: raw S = QK^T -> bf16 LDS (mask applied in Phase C) ----
  for (int st = wv; st < SRC / 16; st += 8) {
    const int sbase = st * 16;
    const unsigned short* kp = kb + (size_t)(sbase + l16) * (BH * HD) + h * HD + quad * 8;
    bf16x8 bk0 = __builtin_bit_cast(bf16x8, *(const ushortx8*)kp);
    bf16x8 bk1 = __builtin_bit_cast(bf16x8, *(const ushortx8*)(kp + 32));
    floatx4 c = {0.f, 0.f, 0.f, 0.f};
    c = __builtin_amdgcn_mfma_f32_16x16x32_bf16(aq[0], bk0, c, 0, 0, 0);
    c = __builtin_amdgcn_mfma_f32_16x16x32_bf16(aq[1], bk1, c, 0, 0, 0);
    const int scol = sbase + l16;
#pragma unroll
    for (int r = 0; r < 4; ++r) {
      const int tl = quad * 4 + r;               // C row = quad*4 + reg
      const float val = c[r];
      const float oth = __shfl_xor(val, 1);      // partner column s^1
      if (!(l16 & 1)) {
        unsigned pk2 = (unsigned)f2bf(val) | ((unsigned)f2bf(oth) << 16);
        *(unsigned*)&smS[tl * SROW + scol] = pk2;
      }
    }
  }
  __syncthreads();

  // ---- Phase C pass 1: apply mask (coalesced), partial row max ----
  {
    const int row = tid >> 5;
    const int cc = tid & 31;
    unsigned short* srow = smS + row * SROW;
    const size_t mbase = (size_t)(t0 + row) * SRC;
    float pmax = -3.4e38f;
#pragma unroll
    for (int kk = 0; kk < 8; ++kk) {
      const int col = cc * 8 + kk * 256;
      ushortx8 u = *(const ushortx8*)&srow[col];
      unsigned mbits[8];
      if (is_u8) {
        uint2 m2 = *(const uint2*)(mask8 + mbase + col);
#pragma unroll
        for (int i = 0; i < 4; ++i) { mbits[i] = (m2.x >> (8 * i)) & 0xFF; mbits[4 + i] = (m2.y >> (8 * i)) & 0xFF; }
      } else {
        const int4 a = *(const int4*)(mask32 + mbase + col);
        const int4 b = *(const int4*)(mask32 + mbase + col + 4);
        mbits[0] = a.x; mbits[1] = a.y; mbits[2] = a.z; mbits[3] = a.w;
        mbits[4] = b.x; mbits[5] = b.y; mbits[6] = b.z; mbits[7] = b.w;
      }
      union { unsigned short u[8]; ushortx8 v; } o;
#pragma unroll
      for (int i = 0; i < 8; ++i) {
        float val = mbits[i] ? -1e8f : bf2f(u[i]);
        pmax = fmaxf(pmax, val);
        o.u[i] = f2bf(val);
      }
      *(ushortx8*)&srow[col] = o.v;
    }
    redArr[row * 32 + cc] = pmax;
  }
  __syncthreads();
  if (tid < BT) {
    float m = -3.4e38f;
    for (int j = 0; j < 32; ++j) m = fmaxf(m, redArr[tid * 32 + j]);
    rowmaxArr[tid] = m;
  }
  __syncthreads();

  // ---- Phase C pass 2: e = exp(S - rowmax), partial sums ----
  {
    const int row = tid >> 5;
    const int cc = tid & 31;
    const float rm = rowmaxArr[row];
    unsigned short* srow = smS + row * SROW;
    float psum = 0.f;
#pragma unroll
    for (int kk = 0; kk < 8; ++kk) {
      const int col = cc * 8 + kk * 256;
      ushortx8 u = *(const ushortx8*)&srow[col];
      union { unsigned short u[8]; ushortx8 v; } o;
#pragma unroll
      for (int i = 0; i < 8; ++i) {
        float e = __expf(bf2f(u[i]) - rm);
        psum += e;
        o.u[i] = f2bf(e);
      }
      *(ushortx8*)&srow[col] = o.v;
    }
    redArr[row * 32 + cc] = psum;
  }
  __syncthreads();
  if (tid < BT) {
    float s = 0.f;
    for (int j = 0; j < 32; ++j) s += redArr[tid * 32 + j];
    invArr[tid] = 1.0f / s;
  }
  __syncthreads();

  // ---- Phase E: stream w = e * inv (stores overlap Phase D compute) ----
  {
    const int row = tid >> 5;
    const int cc = tid & 31;
    const float invv = invArr[row];
    float* wrow = wout + ((size_t)h * TGT + (t0 + row)) * SRC;
    const unsigned short* srow = smS + row * SROW;
#pragma unroll
    for (int kk = 0; kk < 8; ++kk) {
      const int col = cc * 8 + kk * 256;
      ushortx8 u = *(const ushortx8*)&srow[col];
      float4 a, b;
      a.x = bf2f(u[0]) * invv; a.y = bf2f(u[1]) * invv;
      a.z = bf2f(u[2]) * invv; a.w = bf2f(u[3]) * invv;
      b.x = bf2f(u[4]) * invv; b.y = bf2f(u[5]) * invv;
      b.z = bf2f(u[6]) * invv; b.w = bf2f(u[7]) * invv;
      *(float4*)&wrow[col] = a;
      *(float4*)&wrow[col + 4] = b;
    }
  }

  // ---- Phase D: out = (e V) * inv; wave = (s-half, d-tile) ----
  {
    const int dt = wv & 3;
    const int halfsel = wv >> 2;
    const int dbase = dt * 16;
    const int sstart = halfsel * 1024;
    const unsigned short* vp = vtb + (size_t)h * HD * SRC +
                               (size_t)(dbase + l16) * SRC + sstart + quad * 8;
    const unsigned short* sp = smS + l16 * SROW + sstart + quad * 8;
    floatx4 acc = {0.f, 0.f, 0.f, 0.f};
    for (int s0 = 0; s0 < 1024; s0 += 32) {
      bf16x8 af = __builtin_bit_cast(bf16x8, *(const ushortx8*)(sp + s0));
      bf16x8 bfv = __builtin_bit_cast(bf16x8, *(const ushortx8*)(vp + s0));
      acc = __builtin_amdgcn_mfma_f32_16x16x32_bf16(af, bfv, acc, 0, 0, 0);
    }
    if (halfsel) {
#pragma unroll
      for (int r = 0; r < 4; ++r)
        redArr[dt * 256 + (quad * 4 + r) * 16 + l16] = acc[r];
    }
    __syncthreads();
    if (!halfsel) {
#pragma unroll
      for (int r = 0; r < 4; ++r) {
        const int tl = quad * 4 + r;
        float s = acc[r] + redArr[dt * 256 + tl * 16 + l16];
        out0[((size_t)(t0 + tl) * BH + h) * HD + dbase + l16] = s * invArr[tl];
      }
    }
  }
}

extern "C" void kernel_launch(void* const* d_in, const int* in_sizes, int n_in,
                              void* d_out, int out_size, void* d_ws, size_t ws_size,
                              hipStream_t stream) {
  const float* q = (const float*)d_in[0];
  const float* k = (const float*)d_in[1];
  const float* v = (const float*)d_in[2];
  const unsigned char* m8 = (const unsigned char*)d_in[3];
  const int* m32 = (const int*)d_in[3];
  float* out0 = (float*)d_out;
  float* wout = out0 + (size_t)TGT * BH * HD;

  unsigned short* qb = (unsigned short*)d_ws;                 // 4 MB
  unsigned short* kb = qb + (size_t)TGT * BH * HD;            // 4 MB
  unsigned short* vt = kb + (size_t)SRC * BH * HD;            // 4 MB

  const size_t shbytes = (size_t)BT * SROW * 2 + 1024 * 4 + BT * 4 + BT * 4;
  hipFuncSetAttribute((const void*)attn_kernel,
                      hipFuncAttributeMaxDynamicSharedMemorySize, (int)shbytes);

  detect_mask_fmt<<<1, 256, 0, stream>>>(m8);
  cvt_qk<<<dim3(2048), dim3(256), 0, stream>>>(q, k, qb, kb);
  v_tr<<<dim3(BH * (SRC / 64)), dim3(256), 0, stream>>>(v, vt);
  attn_kernel<<<dim3(BH * (TGT / BT)), dim3(512), shbytes, stream>>>(
      qb, kb, vt, m8, m32, out0, wout);
}